// Round 1
// baseline (1281.434 us; speedup 1.0000x reference)
//
#include <hip/hip_runtime.h>
#include <math.h>

#define LR 0.1f
#define EPS 1e-6f

constexpr int B_ = 16, S_ = 4096, DK_ = 256, DV_ = 256;

// ---------------------------------------------------------------------------
// Kernel A: rnorm[b*S + t] = 1 / (||key[b,t,:]|| + EPS)
// One wave (64 lanes) per (b,t) row of 256 floats; lane l loads float4 at 4l.
// ---------------------------------------------------------------------------
__global__ __launch_bounds__(256)
void knorm_kernel(const float* __restrict__ key, float* __restrict__ rnorm) {
    const int wave = (blockIdx.x * blockDim.x + threadIdx.x) >> 6;  // (b*S + t)
    const int lane = threadIdx.x & 63;
    const float4 k4 = reinterpret_cast<const float4*>(key + (size_t)wave * DK_)[lane];
    float s = k4.x * k4.x + k4.y * k4.y + k4.z * k4.z + k4.w * k4.w;
#pragma unroll
    for (int off = 32; off; off >>= 1) s += __shfl_xor(s, off);
    if (lane == 0) rnorm[wave] = 1.0f / (sqrtf(s) + EPS);
}

// ---------------------------------------------------------------------------
// Main kernel: one wave per (batch, output-row). Row recurrences are fully
// independent, so no barriers anywhere. Lane l owns M[b,row,4l..4l+3].
// PRECOMP=true reads 1/(||k||+eps) from rnorm; else computes it in-loop with
// a second interleaved butterfly reduction.
// ---------------------------------------------------------------------------
template <bool PRECOMP>
__global__ __launch_bounds__(256, 4)
void delta_kernel(const float* __restrict__ memory, const float* __restrict__ key,
                  const float* __restrict__ value, const float* __restrict__ rnorm,
                  float* __restrict__ out) {
    const int lane = threadIdx.x & 63;
    const int wid  = threadIdx.x >> 6;
    const int bid  = blockIdx.x;
    const int b    = bid >> 6;                 // 64 blocks per batch
    const int row  = ((bid & 63) << 2) + wid;  // 4 waves/block -> 4 rows/block

    const float* kbase = key   + (size_t)b * S_ * DK_;
    const float* vbase = value + (size_t)b * S_ * DV_ + row;
    const float* rbase = PRECOMP ? (rnorm + (size_t)b * S_) : nullptr;

    float4 m = reinterpret_cast<const float4*>(memory + ((size_t)b * DV_ + row) * DK_)[lane];

    // prefetch k_0
    float4 k = reinterpret_cast<const float4*>(kbase)[lane];

    for (int t = 0; t < S_; ++t) {
        // wave-uniform scalars for this step
        const float v = vbase[(size_t)t * DV_];
        float rn = 0.0f;
        if (PRECOMP) rn = rbase[t];

        // partial dot(M_row, k_t)
        float p = m.x * k.x + m.y * k.y + m.z * k.z + m.w * k.w;
        float s2 = 0.0f;
        if (!PRECOMP) s2 = k.x * k.x + k.y * k.y + k.z * k.z + k.w * k.w;

        // software-prefetch k_{t+1} (clamped; last iter re-reads k_{S-1}, unused)
        const int tn = (t + 1 < S_) ? (t + 1) : (S_ - 1);
        const float4 kn = reinterpret_cast<const float4*>(kbase + (size_t)tn * DK_)[lane];

        // 64-lane butterfly reduction(s)
#pragma unroll
        for (int off = 32; off; off >>= 1) {
            p += __shfl_xor(p, off);
            if (!PRECOMP) s2 += __shfl_xor(s2, off);
        }
        if (!PRECOMP) rn = 1.0f / (sqrtf(s2) + EPS);

        // pred = (M k) * rn ; coeff = (1+LR)*pred - LR*v ; M -= coeff * rn * k
        const float pred  = p * rn;
        const float coeff = (pred + LR * (pred - v)) * rn;
        m.x -= coeff * k.x;
        m.y -= coeff * k.y;
        m.z -= coeff * k.z;
        m.w -= coeff * k.w;

        k = kn;
    }

    reinterpret_cast<float4*>(out + ((size_t)b * DV_ + row) * DK_)[lane] = m;
}

// ---------------------------------------------------------------------------
extern "C" void kernel_launch(void* const* d_in, const int* in_sizes, int n_in,
                              void* d_out, int out_size, void* d_ws, size_t ws_size,
                              hipStream_t stream) {
    const float* memory = (const float*)d_in[0];   // (B, DV, DK) f32
    const float* key    = (const float*)d_in[1];   // (B, S, DK)  f32
    const float* value  = (const float*)d_in[2];   // (B, S, DV)  f32
    float*       out    = (float*)d_out;           // (B, DV, DK) f32
    float*       rnorm  = (float*)d_ws;

    const size_t rnorm_bytes = (size_t)B_ * S_ * sizeof(float);
    const bool precomp = (ws_size >= rnorm_bytes);

    if (precomp) {
        // one wave per (b,t): B*S waves, 4 waves/block
        knorm_kernel<<<(B_ * S_) / 4, 256, 0, stream>>>(key, rnorm);
        delta_kernel<true><<<(B_ * DV_) / 4, 256, 0, stream>>>(memory, key, value, rnorm, out);
    } else {
        delta_kernel<false><<<(B_ * DV_) / 4, 256, 0, stream>>>(memory, key, value, nullptr, out);
    }
}